// Round 4
// baseline (275.704 us; speedup 1.0000x reference)
//
#include <hip/hip_runtime.h>

#define B_ 2
#define T_ 2048
#define C_ 1024
#define H_ 16
#define D_ 64
#define HD_ 1024
#define NBT 4096  // B_*T_

typedef unsigned short u16;
typedef short bf16x8 __attribute__((ext_vector_type(8)));
typedef float f32x4 __attribute__((ext_vector_type(4)));
typedef u16 u16x8 __attribute__((ext_vector_type(8)));

__device__ __forceinline__ u16 f2bf(float f) {
  unsigned u = __float_as_uint(f);
  u += 0x7FFFu + ((u >> 16) & 1u);
  return (u16)(u >> 16);
}

__device__ __forceinline__ void gload16(const void* g, void* l) {
  __builtin_amdgcn_global_load_lds(
      (const __attribute__((address_space(1))) unsigned int*)g,
      (__attribute__((address_space(3))) unsigned int*)l, 16, 0, 0);
}

#define MFMA16(a, b, c) __builtin_amdgcn_mfma_f32_16x16x32_bf16((a), (b), (c), 0, 0, 0)

// ---- prep: modulator -> temp_scale (output 1), scale, diag ---------------
__global__ void prep_kernel(const float* ps, const float* wmod, const float* bmod,
                            float* out_tail, float* scale_buf, float* diag_buf) {
  int t = threadIdx.x;
  if (t < B_ * H_) {
    int b = t >> 4, h = t & 15;
    float p = ps[b];
    float m0 = p * wmod[2 * h] + bmod[2 * h];
    float m1 = p * wmod[2 * h + 1] + bmod[2 * h + 1];
    float sp = (m0 > 20.f) ? m0 : log1pf(expf(m0));
    float temp = 1.f + sp;
    out_tail[t] = temp;                    // temp_scale output
    scale_buf[t] = 1.f / (8.f * temp);     // 1/(sqrt(D)*temp)
    diag_buf[t] = m1;
  }
}

// ---- x: f32 -> bf16 ------------------------------------------------------
__global__ void convert_x(const float* __restrict__ x, u16* __restrict__ xb) {
  int i = blockIdx.x * 256 + threadIdx.x;
  float4 v = ((const float4*)x)[i];
  ushort4 o;
  o.x = f2bf(v.x); o.y = f2bf(v.y); o.z = f2bf(v.z); o.w = f2bf(v.w);
  ((ushort4*)xb)[i] = o;
}

// ---- weights: f32 [K][N] -> bf16 transposed [N][K] -----------------------
__global__ void convert_w_t(const float* w0, const float* w1, const float* w2, const float* w3,
                            u16* t0, u16* t1, u16* t2, u16* t3) {
  const float* w; u16* wt;
  switch (blockIdx.z) {
    case 0: w = w0; wt = t0; break;
    case 1: w = w1; wt = t1; break;
    case 2: w = w2; wt = t2; break;
    default: w = w3; wt = t3; break;
  }
  __shared__ float tile[64][65];
  int k0 = blockIdx.x * 64, n0 = blockIdx.y * 64;
  int tid = threadIdx.x;
  int r = tid >> 4, c = (tid & 15) * 4;
#pragma unroll
  for (int i = 0; i < 4; i++) {
    float4 v = *(const float4*)(w + (size_t)(k0 + r + i * 16) * 1024 + n0 + c);
    tile[r + i * 16][c] = v.x; tile[r + i * 16][c + 1] = v.y;
    tile[r + i * 16][c + 2] = v.z; tile[r + i * 16][c + 3] = v.w;
  }
  __syncthreads();
#pragma unroll
  for (int i = 0; i < 4; i++) {
    int rn = r + i * 16;
    ushort4 o;
    o.x = f2bf(tile[c][rn]); o.y = f2bf(tile[c + 1][rn]);
    o.z = f2bf(tile[c + 2][rn]); o.w = f2bf(tile[c + 3][rn]);
    *(ushort4*)(wt + (size_t)(n0 + rn) * 1024 + k0 + c) = o;
  }
}

// ---- v [B*T][HD] bf16 -> vT [(b*H+h)*64+d][T] bf16 -----------------------
__global__ void transpose_v(const u16* __restrict__ v, u16* __restrict__ vT) {
  __shared__ u16 tile[64][72];
  int st0 = blockIdx.x * 64;
  int hd0 = blockIdx.y * 64;
  int tid = threadIdx.x;
  int r = tid >> 3, c8 = (tid & 7) * 8;
#pragma unroll
  for (int i = 0; i < 2; i++) {
    int rr = r + i * 32;
    u16x8 val = *(const u16x8*)(v + (size_t)(st0 + rr) * HD_ + hd0 + c8);
#pragma unroll
    for (int j = 0; j < 8; j++) tile[rr][c8 + j] = val[j];
  }
  __syncthreads();
  int b = st0 >> 11;
  int s_base = st0 & 2047;
  int h = hd0 >> 6;
#pragma unroll
  for (int i = 0; i < 2; i++) {
    int dl = r + i * 32;
    u16x8 o;
#pragma unroll
    for (int j = 0; j < 8; j++) o[j] = tile[c8 + j][dl];
    *(u16x8*)(vT + (size_t)((b * H_ + h) * 64 + dl) * T_ + s_base + c8) = o;
  }
}

// ---- 128x128 B^T GEMM: C[m][n] = sum_k A[m][k]*BT[n][k] + bias[n] --------
template <int OUT_BF16>
__global__ __launch_bounds__(256) void gemm_bt(const u16* __restrict__ A, const u16* __restrict__ BT,
                                               const float* __restrict__ bias, void* __restrict__ Cout,
                                               int M, int N, int K) {
  __shared__ u16 As[128 * 32];
  __shared__ u16 Bs[128 * 32];
  int m0 = blockIdx.x * 128, n0 = blockIdx.y * 128;
  int tid = threadIdx.x;
  int w = tid >> 6, l = tid & 63;
  int wr = w >> 1, wc = w & 1;
  int lrow = l & 15, kb = l >> 4;
  int r = tid >> 2, c = tid & 3;
  f32x4 acc[4][4] = {};
  for (int k0 = 0; k0 < K; k0 += 32) {
#pragma unroll
    for (int j = 0; j < 2; j++) {
      gload16(A + (size_t)(m0 + r + j * 64) * K + k0 + c * 8, (char*)As + (r + j * 64) * 64 + c * 16);
      gload16(BT + (size_t)(n0 + r + j * 64) * K + k0 + c * 8, (char*)Bs + (r + j * 64) * 64 + c * 16);
    }
    __syncthreads();
    bf16x8 af[4], bfv[4];
#pragma unroll
    for (int mi = 0; mi < 4; mi++) af[mi] = *(const bf16x8*)(As + (wr * 64 + mi * 16 + lrow) * 32 + kb * 8);
#pragma unroll
    for (int ni = 0; ni < 4; ni++) bfv[ni] = *(const bf16x8*)(Bs + (wc * 64 + ni * 16 + lrow) * 32 + kb * 8);
#pragma unroll
    for (int mi = 0; mi < 4; mi++)
#pragma unroll
      for (int ni = 0; ni < 4; ni++) acc[mi][ni] = MFMA16(af[mi], bfv[ni], acc[mi][ni]);
    __syncthreads();
  }
#pragma unroll
  for (int mi = 0; mi < 4; mi++)
#pragma unroll
    for (int ni = 0; ni < 4; ni++) {
      int gcol = n0 + wc * 64 + ni * 16 + lrow;
      float bv = bias[gcol];
#pragma unroll
      for (int rr = 0; rr < 4; rr++) {
        int grow = m0 + wr * 64 + mi * 16 + kb * 4 + rr;
        float val = acc[mi][ni][rr] + bv;
        if (OUT_BF16) ((u16*)Cout)[(size_t)grow * N + gcol] = f2bf(val);
        else ((float*)Cout)[(size_t)grow * N + gcol] = val;
      }
    }
}

// ---- pass 1: per-s row max m[s] and 1/l[s] over t ------------------------
__global__ __launch_bounds__(256) void attn_pass1(const u16* __restrict__ q, const u16* __restrict__ k,
                                                  const int* __restrict__ mask,
                                                  const float* __restrict__ scale_buf,
                                                  const float* __restrict__ diag_buf,
                                                  float* __restrict__ m_buf, float* __restrict__ il_buf) {
  __shared__ u16 Ks[128 * 64];
  __shared__ u16 Qs[128 * 64];
  int bh = blockIdx.x;
  int b = bh >> 4, h = bh & 15;
  int s0 = blockIdx.y * 128;
  int tid = threadIdx.x;
  int w = tid >> 6, l = tid & 63;
  int lrow = l & 15, kb = l >> 4;
  float scale = scale_buf[bh];
  float diagb = diag_buf[bh];
  int sr = tid >> 3, slotL = tid & 7;
#pragma unroll
  for (int j = 0; j < 4; j++) {
    int row = sr + j * 32;
    int slotG = slotL ^ (row & 7);
    gload16(k + (size_t)(b * T_ + s0 + row) * HD_ + h * 64 + slotG * 8,
            (char*)Ks + row * 128 + slotL * 16);
  }
  float m_run[2][4], l_run[2][4];
#pragma unroll
  for (int mi = 0; mi < 2; mi++)
#pragma unroll
    for (int rr = 0; rr < 4; rr++) { m_run[mi][rr] = -3.0e38f; l_run[mi][rr] = 0.f; }

  for (int t0 = 0; t0 < T_; t0 += 128) {
    __syncthreads();
#pragma unroll
    for (int j = 0; j < 4; j++) {
      int row = sr + j * 32;
      int slotG = slotL ^ (row & 7);
      gload16(q + (size_t)(b * T_ + t0 + row) * HD_ + h * 64 + slotG * 8,
              (char*)Qs + row * 128 + slotL * 16);
    }
    __syncthreads();
    f32x4 acc[2][8];
#pragma unroll
    for (int mi = 0; mi < 2; mi++)
#pragma unroll
      for (int ni = 0; ni < 8; ni++) acc[mi][ni] = (f32x4){0.f, 0.f, 0.f, 0.f};
#pragma unroll
    for (int ks = 0; ks < 2; ks++) {
      bf16x8 af[2], bq8[8];
#pragma unroll
      for (int mi = 0; mi < 2; mi++) {
        int row = w * 32 + mi * 16 + lrow;
        int slot = (ks * 4 + kb) ^ (row & 7);
        af[mi] = *(const bf16x8*)(Ks + row * 64 + slot * 8);
      }
#pragma unroll
      for (int ni = 0; ni < 8; ni++) {
        int row = ni * 16 + lrow;
        int slot = (ks * 4 + kb) ^ (row & 7);
        bq8[ni] = *(const bf16x8*)(Qs + row * 64 + slot * 8);
      }
#pragma unroll
      for (int mi = 0; mi < 2; mi++)
#pragma unroll
        for (int ni = 0; ni < 8; ni++) acc[mi][ni] = MFMA16(af[mi], bq8[ni], acc[mi][ni]);
    }
    int tg[8]; float mpen[8];
#pragma unroll
    for (int ni = 0; ni < 8; ni++) {
      tg[ni] = t0 + ni * 16 + lrow;
      mpen[ni] = (mask[(size_t)b * T_ + tg[ni]] != 0) ? 0.f : 1.f;
    }
#pragma unroll
    for (int mi = 0; mi < 2; mi++)
#pragma unroll
      for (int rr = 0; rr < 4; rr++) {
        int sg = s0 + w * 32 + mi * 16 + kb * 4 + rr;
        float sc[8]; float tm = -3.0e38f;
#pragma unroll
        for (int ni = 0; ni < 8; ni++) {
          float xv = acc[mi][ni][rr] * scale;
          if (sg == tg[ni]) xv += diagb;
          if (mpen[ni] != 0.f) xv = -1.0e9f;
          sc[ni] = xv;
          tm = fmaxf(tm, xv);
        }
#pragma unroll
        for (int off = 1; off <= 8; off <<= 1) tm = fmaxf(tm, __shfl_xor(tm, off));
        float es = 0.f;
#pragma unroll
        for (int ni = 0; ni < 8; ni++) es += __expf(sc[ni] - tm);
#pragma unroll
        for (int off = 1; off <= 8; off <<= 1) es += __shfl_xor(es, off);
        float mo = m_run[mi][rr];
        float mn = fmaxf(mo, tm);
        l_run[mi][rr] = l_run[mi][rr] * __expf(mo - mn) + es * __expf(tm - mn);
        m_run[mi][rr] = mn;
      }
  }
#pragma unroll
  for (int mi = 0; mi < 2; mi++)
#pragma unroll
    for (int rr = 0; rr < 4; rr++)
      if (lrow == 0) {
        int sg = s0 + w * 32 + mi * 16 + kb * 4 + rr;
        size_t idx = (size_t)bh * T_ + sg;
        m_buf[idx] = m_run[mi][rr];
        il_buf[idx] = 1.f / l_run[mi][rr];
      }
}

// ---- pass 2: o[t][d] = sum_s exp(S[s][t]-m[s])/l[s] * v[s][d] ------------
__global__ __launch_bounds__(256) void attn_pass2(const u16* __restrict__ q, const u16* __restrict__ k,
                                                  const u16* __restrict__ vT,
                                                  const int* __restrict__ mask,
                                                  const float* __restrict__ scale_buf,
                                                  const float* __restrict__ diag_buf,
                                                  const float* __restrict__ m_buf,
                                                  const float* __restrict__ il_buf,
                                                  u16* __restrict__ o) {
  __shared__ u16 Qs[128 * 64];
  __shared__ u16 Ks[64 * 64];
  __shared__ u16 Vs[64 * 64];
  __shared__ u16 Ps[128 * 64];
  int bh = blockIdx.x;
  int b = bh >> 4, h = bh & 15;
  int t0 = blockIdx.y * 128;
  int tid = threadIdx.x;
  int w = tid >> 6, l = tid & 63;
  int lrow = l & 15, kb = l >> 4;
  float scale = scale_buf[bh];
  float diagb = diag_buf[bh];
  int sr = tid >> 3, slotL = tid & 7;
#pragma unroll
  for (int j = 0; j < 4; j++) {
    int row = sr + j * 32;
    int slotG = slotL ^ (row & 7);
    gload16(q + (size_t)(b * T_ + t0 + row) * HD_ + h * 64 + slotG * 8,
            (char*)Qs + row * 128 + slotL * 16);
  }
  bool tmask[2][4];
#pragma unroll
  for (int mi = 0; mi < 2; mi++)
#pragma unroll
    for (int rr = 0; rr < 4; rr++)
      tmask[mi][rr] = mask[(size_t)b * T_ + t0 + w * 32 + mi * 16 + kb * 4 + rr] != 0;
  f32x4 oacc[2][4] = {};
  for (int s0 = 0; s0 < T_; s0 += 64) {
    __syncthreads();
#pragma unroll
    for (int j = 0; j < 2; j++) {
      int row = sr + j * 32;
      int slotG = slotL ^ (row & 7);
      gload16(k + (size_t)(b * T_ + s0 + row) * HD_ + h * 64 + slotG * 8,
              (char*)Ks + row * 128 + slotL * 16);
      gload16(vT + (size_t)(bh * 64 + row) * T_ + s0 + slotG * 8,
              (char*)Vs + row * 128 + slotL * 16);
    }
    __syncthreads();
    f32x4 sacc[2][4] = {};
#pragma unroll
    for (int ks = 0; ks < 2; ks++) {
      bf16x8 af[2], bk8[4];
#pragma unroll
      for (int mi = 0; mi < 2; mi++) {
        int row = w * 32 + mi * 16 + lrow;
        int slot = (ks * 4 + kb) ^ (row & 7);
        af[mi] = *(const bf16x8*)(Qs + row * 64 + slot * 8);
      }
#pragma unroll
      for (int ni = 0; ni < 4; ni++) {
        int row = ni * 16 + lrow;
        int slot = (ks * 4 + kb) ^ (row & 7);
        bk8[ni] = *(const bf16x8*)(Ks + row * 64 + slot * 8);
      }
#pragma unroll
      for (int mi = 0; mi < 2; mi++)
#pragma unroll
        for (int ni = 0; ni < 4; ni++) sacc[mi][ni] = MFMA16(af[mi], bk8[ni], sacc[mi][ni]);
    }
    float mv[4], ilv[4];
#pragma unroll
    for (int ni = 0; ni < 4; ni++) {
      size_t idx = (size_t)bh * T_ + s0 + ni * 16 + lrow;
      mv[ni] = m_buf[idx];
      ilv[ni] = il_buf[idx];
    }
#pragma unroll
    for (int mi = 0; mi < 2; mi++)
#pragma unroll
      for (int rr = 0; rr < 4; rr++) {
        int t_loc = w * 32 + mi * 16 + kb * 4 + rr;
        int tg = t0 + t_loc;
#pragma unroll
        for (int ni = 0; ni < 4; ni++) {
          int s_loc = ni * 16 + lrow;
          int sg = s0 + s_loc;
          float xv = sacc[mi][ni][rr] * scale;
          if (tg == sg) xv += diagb;
          if (!tmask[mi][rr]) xv = -1.0e9f;
          float p = __expf(xv - mv[ni]) * ilv[ni];
          Ps[t_loc * 64 + (((s_loc >> 3) ^ (t_loc & 7)) * 8) + (s_loc & 7)] = f2bf(p);
        }
      }
    __syncthreads();
#pragma unroll
    for (int ks = 0; ks < 2; ks++) {
      bf16x8 af[2], bv8[4];
#pragma unroll
      for (int mi = 0; mi < 2; mi++) {
        int row = w * 32 + mi * 16 + lrow;
        int slot = (ks * 4 + kb) ^ (row & 7);
        af[mi] = *(const bf16x8*)(Ps + row * 64 + slot * 8);
      }
#pragma unroll
      for (int ni = 0; ni < 4; ni++) {
        int row = ni * 16 + lrow;
        int slot = (ks * 4 + kb) ^ (row & 7);
        bv8[ni] = *(const bf16x8*)(Vs + row * 64 + slot * 8);
      }
#pragma unroll
      for (int mi = 0; mi < 2; mi++)
#pragma unroll
        for (int ni = 0; ni < 4; ni++) oacc[mi][ni] = MFMA16(af[mi], bv8[ni], oacc[mi][ni]);
    }
  }
#pragma unroll
  for (int mi = 0; mi < 2; mi++)
#pragma unroll
    for (int ni = 0; ni < 4; ni++)
#pragma unroll
      for (int rr = 0; rr < 4; rr++) {
        int tg = t0 + w * 32 + mi * 16 + kb * 4 + rr;
        int d = ni * 16 + lrow;
        o[(size_t)(b * T_ + tg) * HD_ + h * 64 + d] = f2bf(oacc[mi][ni][rr]);
      }
}

extern "C" void kernel_launch(void* const* d_in, const int* in_sizes, int n_in,
                              void* d_out, int out_size, void* d_ws, size_t ws_size,
                              hipStream_t stream) {
  const float* x = (const float*)d_in[0];
  const int* mask = (const int*)d_in[1];
  const float* ps = (const float*)d_in[2];
  const float* wq = (const float*)d_in[3];
  const float* bq = (const float*)d_in[4];
  const float* wk = (const float*)d_in[5];
  const float* bk = (const float*)d_in[6];
  const float* wv = (const float*)d_in[7];
  const float* bv = (const float*)d_in[8];
  const float* wmod = (const float*)d_in[9];
  const float* bmod = (const float*)d_in[10];
  const float* wo = (const float*)d_in[11];
  const float* bo = (const float*)d_in[12];
  float* out = (float*)d_out;

  char* ws = (char*)d_ws;
  u16* xb    = (u16*)(ws + 0);
  u16* wqT   = (u16*)(ws + 8388608);
  u16* wkT   = (u16*)(ws + 10485760);
  u16* wvT   = (u16*)(ws + 12582912);
  u16* woT   = (u16*)(ws + 14680064);
  u16* qb    = (u16*)(ws + 16777216);
  u16* kbf   = (u16*)(ws + 25165824);
  u16* vb    = (u16*)(ws + 33554432);
  u16* vTb   = (u16*)(ws + 41943040);
  u16* ob    = (u16*)(ws + 50331648);
  float* m_buf     = (float*)(ws + 58720256);
  float* il_buf    = (float*)(ws + 58982400);
  float* scale_buf = (float*)(ws + 59244544);
  float* diag_buf  = (float*)(ws + 59244672);

  prep_kernel<<<1, 64, 0, stream>>>(ps, wmod, bmod, out + (size_t)B_ * T_ * C_, scale_buf, diag_buf);
  convert_x<<<4096, 256, 0, stream>>>(x, xb);
  convert_w_t<<<dim3(16, 16, 4), 256, 0, stream>>>(wq, wk, wv, wo, wqT, wkT, wvT, woT);
  gemm_bt<1><<<dim3(32, 8), 256, 0, stream>>>(xb, wqT, bq, qb, NBT, HD_, C_);
  gemm_bt<1><<<dim3(32, 8), 256, 0, stream>>>(xb, wkT, bk, kbf, NBT, HD_, C_);
  gemm_bt<1><<<dim3(32, 8), 256, 0, stream>>>(xb, wvT, bv, vb, NBT, HD_, C_);
  transpose_v<<<dim3(64, 16), 256, 0, stream>>>(vb, vTb);
  attn_pass1<<<dim3(32, 16), 256, 0, stream>>>(qb, kbf, mask, scale_buf, diag_buf, m_buf, il_buf);
  attn_pass2<<<dim3(32, 16), 256, 0, stream>>>(qb, kbf, vTb, mask, scale_buf, diag_buf, m_buf, il_buf, ob);
  gemm_bt<0><<<dim3(32, 8), 256, 0, stream>>>(ob, woT, bo, out, NBT, C_, C_);
}

// Round 5
// 199.387 us; speedup vs baseline: 1.3828x; 1.3828x over previous
//
#include <hip/hip_runtime.h>

#define B_ 2
#define T_ 2048
#define C_ 1024
#define H_ 16
#define HD_ 1024
#define NBT 4096  // B_*T_
#define QLD 3072  // fused qkv row stride

typedef unsigned short u16;
typedef short bf16x8 __attribute__((ext_vector_type(8)));
typedef float f32x4 __attribute__((ext_vector_type(4)));

__device__ __forceinline__ u16 f2bf(float f) {
  unsigned u = __float_as_uint(f);
  u += 0x7FFFu + ((u >> 16) & 1u);
  return (u16)(u >> 16);
}
__device__ __forceinline__ float bf2f(u16 h) { return __uint_as_float(((unsigned)h) << 16); }

__device__ __forceinline__ void gload16(const void* g, void* l) {
  __builtin_amdgcn_global_load_lds(
      (const __attribute__((address_space(1))) unsigned int*)g,
      (__attribute__((address_space(3))) unsigned int*)l, 16, 0, 0);
}

#define MFMA16(a, b, c) __builtin_amdgcn_mfma_f32_16x16x32_bf16((a), (b), (c), 0, 0, 0)

// ---- prep: modulator -> temp_scale (output 1), scale, diag ---------------
__global__ void prep_kernel(const float* ps, const float* wmod, const float* bmod,
                            float* out_tail, float* scale_buf, float* diag_buf) {
  int t = threadIdx.x;
  if (t < B_ * H_) {
    int b = t >> 4, h = t & 15;
    float p = ps[b];
    float m0 = p * wmod[2 * h] + bmod[2 * h];
    float m1 = p * wmod[2 * h + 1] + bmod[2 * h + 1];
    float sp = (m0 > 20.f) ? m0 : log1pf(expf(m0));
    float temp = 1.f + sp;
    out_tail[t] = temp;                 // temp_scale output
    scale_buf[t] = 1.f / (8.f * temp);  // folded into q at gemm epilogue
    diag_buf[t] = m1;
  }
}

// ---- x: f32 -> bf16 ------------------------------------------------------
__global__ void convert_x(const float* __restrict__ x, u16* __restrict__ xb) {
  int i = blockIdx.x * 256 + threadIdx.x;
  float4 v = ((const float4*)x)[i];
  ushort4 o;
  o.x = f2bf(v.x); o.y = f2bf(v.y); o.z = f2bf(v.z); o.w = f2bf(v.w);
  ((ushort4*)xb)[i] = o;
}

// ---- weights: f32 [K][N] -> bf16 transposed; q,k,v fused [3072][1024] ----
__global__ void convert_w_t(const float* wq, const float* wk, const float* wv,
                            const float* wo, u16* qkvT, u16* woT) {
  int z = blockIdx.z;
  const float* w = (z == 0) ? wq : (z == 1) ? wk : (z == 2) ? wv : wo;
  u16* wt = (z == 3) ? woT : qkvT + (size_t)z * 1024 * 1024;
  __shared__ float tile[64][65];
  int k0 = blockIdx.x * 64, n0 = blockIdx.y * 64;
  int tid = threadIdx.x;
  int r = tid >> 4, c = (tid & 15) * 4;
#pragma unroll
  for (int i = 0; i < 4; i++) {
    float4 v = *(const float4*)(w + (size_t)(k0 + r + i * 16) * 1024 + n0 + c);
    tile[r + i * 16][c] = v.x; tile[r + i * 16][c + 1] = v.y;
    tile[r + i * 16][c + 2] = v.z; tile[r + i * 16][c + 3] = v.w;
  }
  __syncthreads();
#pragma unroll
  for (int i = 0; i < 4; i++) {
    int rn = r + i * 16;
    ushort4 o;
    o.x = f2bf(tile[c][rn]); o.y = f2bf(tile[c + 1][rn]);
    o.z = f2bf(tile[c + 2][rn]); o.w = f2bf(tile[c + 3][rn]);
    *(ushort4*)(wt + (size_t)(n0 + rn) * 1024 + k0 + c) = o;
  }
}

// ---- fused QKV GEMM: qkv[m][n] = x*W^T + bias; q cols pre-scaled ---------
__global__ __launch_bounds__(256) void gemm_qkv(const u16* __restrict__ A, const u16* __restrict__ BT,
                                                const float* __restrict__ bq, const float* __restrict__ bk,
                                                const float* __restrict__ bv,
                                                const float* __restrict__ scale_buf,
                                                u16* __restrict__ Cout) {
  __shared__ u16 As[128 * 32];
  __shared__ u16 Bs[128 * 32];
  int m0 = blockIdx.x * 128, n0 = blockIdx.y * 128;
  int tid = threadIdx.x;
  int w = tid >> 6, l = tid & 63;
  int wr = w >> 1, wc = w & 1;
  int lrow = l & 15, kb = l >> 4;
  int r = tid >> 2, c = tid & 3;
  f32x4 acc[4][4] = {};
  for (int k0 = 0; k0 < C_; k0 += 32) {
#pragma unroll
    for (int j = 0; j < 2; j++) {
      gload16(A + (size_t)(m0 + r + j * 64) * C_ + k0 + c * 8, (char*)As + (r + j * 64) * 64 + c * 16);
      gload16(BT + (size_t)(n0 + r + j * 64) * C_ + k0 + c * 8, (char*)Bs + (r + j * 64) * 64 + c * 16);
    }
    __syncthreads();
    bf16x8 af[4], bfv[4];
#pragma unroll
    for (int mi = 0; mi < 4; mi++) af[mi] = *(const bf16x8*)(As + (wr * 64 + mi * 16 + lrow) * 32 + kb * 8);
#pragma unroll
    for (int ni = 0; ni < 4; ni++) bfv[ni] = *(const bf16x8*)(Bs + (wc * 64 + ni * 16 + lrow) * 32 + kb * 8);
#pragma unroll
    for (int mi = 0; mi < 4; mi++)
#pragma unroll
      for (int ni = 0; ni < 4; ni++) acc[mi][ni] = MFMA16(af[mi], bfv[ni], acc[mi][ni]);
    __syncthreads();
  }
  int bb = m0 >> 11;
#pragma unroll
  for (int mi = 0; mi < 4; mi++)
#pragma unroll
    for (int ni = 0; ni < 4; ni++) {
      int gcol = n0 + wc * 64 + ni * 16 + lrow;
      int sect = gcol >> 10;
      const float* bp = (sect == 0) ? bq : (sect == 1) ? bk : bv;
      float bvf = bp[gcol & 1023];
      float fac = (sect == 0) ? scale_buf[bb * 16 + ((gcol >> 6) & 15)] : 1.f;
#pragma unroll
      for (int rr = 0; rr < 4; rr++) {
        int grow = m0 + wr * 64 + mi * 16 + kb * 4 + rr;
        Cout[(size_t)grow * QLD + gcol] = f2bf((acc[mi][ni][rr] + bvf) * fac);
      }
    }
}

// ---- generic 128x128 B^T GEMM, f32 out (out-projection) ------------------
__global__ __launch_bounds__(256) void gemm_bt_f32(const u16* __restrict__ A, const u16* __restrict__ BT,
                                                   const float* __restrict__ bias, float* __restrict__ Cout,
                                                   int N, int K) {
  __shared__ u16 As[128 * 32];
  __shared__ u16 Bs[128 * 32];
  int m0 = blockIdx.x * 128, n0 = blockIdx.y * 128;
  int tid = threadIdx.x;
  int w = tid >> 6, l = tid & 63;
  int wr = w >> 1, wc = w & 1;
  int lrow = l & 15, kb = l >> 4;
  int r = tid >> 2, c = tid & 3;
  f32x4 acc[4][4] = {};
  for (int k0 = 0; k0 < K; k0 += 32) {
#pragma unroll
    for (int j = 0; j < 2; j++) {
      gload16(A + (size_t)(m0 + r + j * 64) * K + k0 + c * 8, (char*)As + (r + j * 64) * 64 + c * 16);
      gload16(BT + (size_t)(n0 + r + j * 64) * K + k0 + c * 8, (char*)Bs + (r + j * 64) * 64 + c * 16);
    }
    __syncthreads();
    bf16x8 af[4], bfv[4];
#pragma unroll
    for (int mi = 0; mi < 4; mi++) af[mi] = *(const bf16x8*)(As + (wr * 64 + mi * 16 + lrow) * 32 + kb * 8);
#pragma unroll
    for (int ni = 0; ni < 4; ni++) bfv[ni] = *(const bf16x8*)(Bs + (wc * 64 + ni * 16 + lrow) * 32 + kb * 8);
#pragma unroll
    for (int mi = 0; mi < 4; mi++)
#pragma unroll
      for (int ni = 0; ni < 4; ni++) acc[mi][ni] = MFMA16(af[mi], bfv[ni], acc[mi][ni]);
    __syncthreads();
  }
#pragma unroll
  for (int mi = 0; mi < 4; mi++)
#pragma unroll
    for (int ni = 0; ni < 4; ni++) {
      int gcol = n0 + wc * 64 + ni * 16 + lrow;
      float bvf = bias[gcol];
#pragma unroll
      for (int rr = 0; rr < 4; rr++) {
        int grow = m0 + wr * 64 + mi * 16 + kb * 4 + rr;
        Cout[(size_t)grow * N + gcol] = acc[mi][ni][rr] + bvf;
      }
    }
}

// ---- pass 1: partial l[s] = sum_t exp(S[s][t]) over half the t range -----
__global__ __launch_bounds__(256) void attn_pass1(const u16* __restrict__ q, const u16* __restrict__ k,
                                                  const int* __restrict__ mask,
                                                  const float* __restrict__ diag_buf,
                                                  float* __restrict__ l_part) {
  __shared__ u16 Ks[128 * 64];
  __shared__ u16 Qs[128 * 64];
  int bh = blockIdx.x, b = bh >> 4, h = bh & 15;
  int s0 = blockIdx.y * 128;
  int half = blockIdx.z;
  int tid = threadIdx.x, w = tid >> 6, l = tid & 63;
  int lrow = l & 15, kb = l >> 4;
  float diagb = diag_buf[bh];
  int sr = tid >> 3, slotL = tid & 7;
#pragma unroll
  for (int j = 0; j < 4; j++) {
    int row = sr + j * 32;
    int slotG = slotL ^ (row & 7);
    gload16(k + (size_t)(b * T_ + s0 + row) * QLD + h * 64 + slotG * 8,
            (char*)Ks + row * 128 + slotL * 16);
  }
  float l_run[2][4] = {};
  for (int tt = 0; tt < 8; tt++) {
    int t0 = half * 1024 + tt * 128;
    __syncthreads();
#pragma unroll
    for (int j = 0; j < 4; j++) {
      int row = sr + j * 32;
      int slotG = slotL ^ (row & 7);
      gload16(q + (size_t)(b * T_ + t0 + row) * QLD + h * 64 + slotG * 8,
              (char*)Qs + row * 128 + slotL * 16);
    }
    __syncthreads();
    f32x4 acc[2][8] = {};
#pragma unroll
    for (int ks = 0; ks < 2; ks++) {
      bf16x8 af[2], bq8[8];
#pragma unroll
      for (int mi = 0; mi < 2; mi++) {
        int row = w * 32 + mi * 16 + lrow;
        int slot = (ks * 4 + kb) ^ (row & 7);
        af[mi] = *(const bf16x8*)(Ks + row * 64 + slot * 8);
      }
#pragma unroll
      for (int ni = 0; ni < 8; ni++) {
        int row = ni * 16 + lrow;
        int slot = (ks * 4 + kb) ^ (row & 7);
        bq8[ni] = *(const bf16x8*)(Qs + row * 64 + slot * 8);
      }
#pragma unroll
      for (int mi = 0; mi < 2; mi++)
#pragma unroll
        for (int ni = 0; ni < 8; ni++) acc[mi][ni] = MFMA16(af[mi], bq8[ni], acc[mi][ni]);
    }
    float mpen[8];
    int mall = 1;
#pragma unroll
    for (int ni = 0; ni < 8; ni++) {
      int mv = mask[b * T_ + t0 + ni * 16 + lrow];
      mpen[ni] = mv ? 1.f : 0.f;
      mall &= (mv != 0);
    }
    bool allset = (~__ballot(mall)) == 0ull;
    bool diagtile = (t0 == s0);
#pragma unroll
    for (int mi = 0; mi < 2; mi++)
#pragma unroll
      for (int rr = 0; rr < 4; rr++) {
        float es = 0.f;
        if (diagtile) {
          int srow = w * 32 + mi * 16 + kb * 4 + rr;
#pragma unroll
          for (int ni = 0; ni < 8; ni++) {
            float xv = acc[mi][ni][rr];
            if (srow == ni * 16 + lrow) xv += diagb;
            float e = __expf(xv);
            if (!allset) e *= mpen[ni];
            es += e;
          }
        } else if (allset) {
#pragma unroll
          for (int ni = 0; ni < 8; ni++) es += __expf(acc[mi][ni][rr]);
        } else {
#pragma unroll
          for (int ni = 0; ni < 8; ni++) es += mpen[ni] * __expf(acc[mi][ni][rr]);
        }
#pragma unroll
        for (int off = 1; off <= 8; off <<= 1) es += __shfl_xor(es, off);
        l_run[mi][rr] += es;
      }
  }
#pragma unroll
  for (int mi = 0; mi < 2; mi++)
#pragma unroll
    for (int rr = 0; rr < 4; rr++)
      if (lrow == 0) {
        int sg = s0 + w * 32 + mi * 16 + kb * 4 + rr;
        l_part[half * (32 * 2048) + bh * 2048 + sg] = l_run[mi][rr];
      }
}

// ---- v (cols 2048.. of qkv) scaled by 1/l, transposed -> vT --------------
__global__ void scale_transpose_v(const u16* __restrict__ qkv, const float* __restrict__ l_part,
                                  u16* __restrict__ vT) {
  __shared__ float tile[64][65];
  int st0 = blockIdx.x * 64;
  int hd0 = blockIdx.y * 64;
  int tid = threadIdx.x;
  int r = tid >> 4, c4 = (tid & 15) * 4;
#pragma unroll
  for (int i = 0; i < 4; i++) {
    int row = r + i * 16;
    ushort4 hh = *(const ushort4*)(qkv + (size_t)(st0 + row) * QLD + 2048 + hd0 + c4);
    tile[row][c4] = bf2f(hh.x); tile[row][c4 + 1] = bf2f(hh.y);
    tile[row][c4 + 2] = bf2f(hh.z); tile[row][c4 + 3] = bf2f(hh.w);
  }
  __syncthreads();
  int b = st0 >> 11, sbase = st0 & 2047, h = hd0 >> 6, bh = b * 16 + h;
#pragma unroll
  for (int i = 0; i < 4; i++) {
    int dl = r + i * 16;
    ushort4 o4;
#pragma unroll
    for (int j = 0; j < 4; j++) {
      int s = sbase + c4 + j;
      float il = 1.f / (l_part[bh * 2048 + s] + l_part[32 * 2048 + bh * 2048 + s]);
      ((u16*)&o4)[j] = f2bf(tile[c4 + j][dl] * il);
    }
    *(ushort4*)(vT + (size_t)(bh * 64 + dl) * T_ + sbase + c4) = o4;
  }
}

// ---- pass 2: o[t][d] = sum_s exp(S[s][t]) * vT'[d][s] --------------------
__global__ __launch_bounds__(256) void attn_pass2(const u16* __restrict__ q, const u16* __restrict__ k,
                                                  const u16* __restrict__ vT,
                                                  const int* __restrict__ mask,
                                                  const float* __restrict__ diag_buf,
                                                  u16* __restrict__ o) {
  __shared__ u16 Qs[64 * 64], Ks[64 * 64], Vs[64 * 64], Ps[64 * 64];
  int bh = blockIdx.x, b = bh >> 4, h = bh & 15;
  int t0 = blockIdx.y * 64;
  int tid = threadIdx.x, w = tid >> 6, l = tid & 63;
  int lrow = l & 15, kb = l >> 4;
  float diagb = diag_buf[bh];
  int sr = tid >> 3, slotL = tid & 7;
#pragma unroll
  for (int j = 0; j < 2; j++) {
    int row = sr + j * 32;
    int slotG = slotL ^ (row & 7);
    gload16(q + (size_t)(b * T_ + t0 + row) * QLD + h * 64 + slotG * 8,
            (char*)Qs + row * 128 + slotL * 16);
  }
  float tm[4];
  int mall = 1;
#pragma unroll
  for (int rr = 0; rr < 4; rr++) {
    int mv = mask[b * T_ + t0 + w * 16 + kb * 4 + rr];
    tm[rr] = mv ? 1.f : 0.f;
    mall &= (mv != 0);
  }
  bool allset = (~__ballot(mall)) == 0ull;
  f32x4 oacc[4] = {};
  for (int s0 = 0; s0 < T_; s0 += 64) {
    __syncthreads();
#pragma unroll
    for (int j = 0; j < 2; j++) {
      int row = sr + j * 32;
      int slotG = slotL ^ (row & 7);
      gload16(k + (size_t)(b * T_ + s0 + row) * QLD + h * 64 + slotG * 8,
              (char*)Ks + row * 128 + slotL * 16);
      gload16(vT + (size_t)(bh * 64 + row) * T_ + s0 + slotG * 8,
              (char*)Vs + row * 128 + slotL * 16);
    }
    __syncthreads();
    f32x4 sacc[4] = {};
#pragma unroll
    for (int ks = 0; ks < 2; ks++) {
      int arow = w * 16 + lrow;
      int aslot = (ks * 4 + kb) ^ (arow & 7);
      bf16x8 aq = *(const bf16x8*)(Qs + arow * 64 + aslot * 8);
#pragma unroll
      for (int ni = 0; ni < 4; ni++) {
        int brow = ni * 16 + lrow;
        int bslot = (ks * 4 + kb) ^ (brow & 7);
        bf16x8 bk = *(const bf16x8*)(Ks + brow * 64 + bslot * 8);
        sacc[ni] = MFMA16(aq, bk, sacc[ni]);
      }
    }
    bool diagtile = (s0 == t0);
#pragma unroll
    for (int ni = 0; ni < 4; ni++)
#pragma unroll
      for (int rr = 0; rr < 4; rr++) {
        int t_loc = w * 16 + kb * 4 + rr;
        int s_loc = ni * 16 + lrow;
        float xv = sacc[ni][rr];
        if (diagtile && (t_loc == s_loc)) xv += diagb;
        float p = __expf(xv);
        if (!allset) p *= tm[rr];
        Ps[t_loc * 64 + (((s_loc >> 3) ^ (t_loc & 7)) * 8) + (s_loc & 7)] = f2bf(p);
      }
    __syncthreads();
#pragma unroll
    for (int ks = 0; ks < 2; ks++) {
      int arow = w * 16 + lrow;
      int aslot = (ks * 4 + kb) ^ (arow & 7);
      bf16x8 ap = *(const bf16x8*)(Ps + arow * 64 + aslot * 8);
#pragma unroll
      for (int ni = 0; ni < 4; ni++) {
        int brow = ni * 16 + lrow;
        int bslot = (ks * 4 + kb) ^ (brow & 7);
        bf16x8 bv = *(const bf16x8*)(Vs + brow * 64 + bslot * 8);
        oacc[ni] = MFMA16(ap, bv, oacc[ni]);
      }
    }
  }
#pragma unroll
  for (int ni = 0; ni < 4; ni++)
#pragma unroll
    for (int rr = 0; rr < 4; rr++) {
      int tg = t0 + w * 16 + kb * 4 + rr;
      int d = ni * 16 + lrow;
      o[(size_t)(b * T_ + tg) * HD_ + h * 64 + d] = f2bf(oacc[ni][rr]);
    }
}

extern "C" void kernel_launch(void* const* d_in, const int* in_sizes, int n_in,
                              void* d_out, int out_size, void* d_ws, size_t ws_size,
                              hipStream_t stream) {
  const float* x = (const float*)d_in[0];
  const int* mask = (const int*)d_in[1];
  const float* ps = (const float*)d_in[2];
  const float* wq = (const float*)d_in[3];
  const float* bq = (const float*)d_in[4];
  const float* wk = (const float*)d_in[5];
  const float* bk = (const float*)d_in[6];
  const float* wv = (const float*)d_in[7];
  const float* bv = (const float*)d_in[8];
  const float* wmod = (const float*)d_in[9];
  const float* bmod = (const float*)d_in[10];
  const float* wo = (const float*)d_in[11];
  const float* bo = (const float*)d_in[12];
  float* out = (float*)d_out;

  const size_t MB = 1ull << 20;
  char* ws = (char*)d_ws;
  u16* xb    = (u16*)(ws + 0 * MB);   // 8 MB
  u16* qkvT  = (u16*)(ws + 8 * MB);   // 6 MB
  u16* woT   = (u16*)(ws + 14 * MB);  // 2 MB
  u16* qkv   = (u16*)(ws + 16 * MB);  // 24 MB
  u16* vT    = (u16*)(ws + 40 * MB);  // 8 MB
  u16* ob    = (u16*)(ws + 48 * MB);  // 8 MB
  float* l_part    = (float*)(ws + 56 * MB);            // 512 KB (2 halves)
  float* scale_buf = (float*)(ws + 56 * MB + 0x80000);  // 128 B
  float* diag_buf  = (float*)(ws + 56 * MB + 0x80100);  // 128 B

  prep_kernel<<<1, 64, 0, stream>>>(ps, wmod, bmod, out + (size_t)B_ * T_ * C_, scale_buf, diag_buf);
  convert_x<<<4096, 256, 0, stream>>>(x, xb);
  convert_w_t<<<dim3(16, 16, 4), 256, 0, stream>>>(wq, wk, wv, wo, qkvT, woT);
  gemm_qkv<<<dim3(32, 24), 256, 0, stream>>>(xb, qkvT, bq, bk, bv, scale_buf, qkv);
  attn_pass1<<<dim3(32, 16, 2), 256, 0, stream>>>(qkv, qkv + 1024, mask, diag_buf, l_part);
  scale_transpose_v<<<dim3(64, 16), 256, 0, stream>>>(qkv, l_part, vT);
  attn_pass2<<<dim3(32, 32), 256, 0, stream>>>(qkv, qkv + 1024, vT, mask, diag_buf, ob);
  gemm_bt_f32<<<dim3(32, 8), 256, 0, stream>>>(ob, woT, bo, out, C_, C_);
}